// Round 10
// baseline (179.779 us; speedup 1.0000x reference)
//
#include <hip/hip_runtime.h>
#include <hip/hip_bf16.h>
#include <stdint.h>

#define M_TOT 16384
#define N_TOT 2048
#define K_TOT 2048
#define NT 32            // K-tiles of BK=64

typedef __attribute__((ext_vector_type(8))) short bf16x8;
typedef __attribute__((ext_vector_type(4))) float f32x4;

__device__ __forceinline__ ushort f32_to_bf16_rne(float f) {
    uint32_t u = __float_as_uint(f);
    uint32_t r = (u + 0x7fffu + ((u >> 16) & 1u)) >> 16;
    return (ushort)r;
}

__device__ __forceinline__ void async_copy16(const void* gptr, void* lptr) {
    __builtin_amdgcn_global_load_lds(
        (const __attribute__((address_space(1))) uint32_t*)gptr,
        (__attribute__((address_space(3))) uint32_t*)lptr,
        16, 0, 0);
}

// ---------------------------------------------------------------------------
// Fake-quantize x: per (row, 32-col) block, symmetric int8 -> bf16.
// ---------------------------------------------------------------------------
__global__ void quant_x_kernel(const float* __restrict__ x, ushort* __restrict__ qx) {
    const int tid = blockIdx.x * 256 + threadIdx.x;
    const float4 v = ((const float4*)x)[tid];
    float m = fmaxf(fmaxf(fabsf(v.x), fabsf(v.y)), fmaxf(fabsf(v.z), fabsf(v.w)));
    m = fmaxf(m, __shfl_xor(m, 1));
    m = fmaxf(m, __shfl_xor(m, 2));
    m = fmaxf(m, __shfl_xor(m, 4));
    const float s = (m > 0.f) ? (m / 127.f) : 1.f;
    const float q0 = fminf(fmaxf(rintf(v.x / s), -127.f), 127.f) * s;
    const float q1 = fminf(fmaxf(rintf(v.y / s), -127.f), 127.f) * s;
    const float q2 = fminf(fmaxf(rintf(v.z / s), -127.f), 127.f) * s;
    const float q3 = fminf(fmaxf(rintf(v.w / s), -127.f), 127.f) * s;
    ushort4 r;
    r.x = f32_to_bf16_rne(q0);
    r.y = f32_to_bf16_rne(q1);
    r.z = f32_to_bf16_rne(q2);
    r.w = f32_to_bf16_rne(q3);
    ((ushort4*)qx)[tid] = r;
}

// ---------------------------------------------------------------------------
// Fake-quantize weight (kept [Dout][Din] == B^T layout). 32x32 blocks.
// ---------------------------------------------------------------------------
__global__ void quant_w_kernel(const float* __restrict__ w, ushort* __restrict__ qw) {
    const int gtid = blockIdx.x * 256 + threadIdx.x;
    const int wid  = gtid >> 6;
    const int lane = gtid & 63;
    const int tn = wid >> 6;
    const int tk = wid & 63;
    const int row = tn * 32 + (lane >> 1);
    const int col = tk * 32 + ((lane & 1) << 4);
    const float* p = w + (size_t)row * K_TOT + col;
    const float4 v0 = ((const float4*)p)[0];
    const float4 v1 = ((const float4*)p)[1];
    const float4 v2 = ((const float4*)p)[2];
    const float4 v3 = ((const float4*)p)[3];
    float m = 0.f;
#define MAX4(V) m = fmaxf(m, fmaxf(fmaxf(fabsf(V.x), fabsf(V.y)), fmaxf(fabsf(V.z), fabsf(V.w))));
    MAX4(v0) MAX4(v1) MAX4(v2) MAX4(v3)
#undef MAX4
    #pragma unroll
    for (int off = 1; off < 64; off <<= 1) m = fmaxf(m, __shfl_xor(m, off));
    const float s = (m > 0.f) ? (m / 127.f) : 1.f;
    float vv[16] = {v0.x, v0.y, v0.z, v0.w, v1.x, v1.y, v1.z, v1.w,
                    v2.x, v2.y, v2.z, v2.w, v3.x, v3.y, v3.z, v3.w};
    union { ushort us[16]; uint4 q[2]; } o;
    #pragma unroll
    for (int i = 0; i < 16; ++i) {
        const float q = fminf(fmaxf(rintf(vv[i] / s), -127.f), 127.f) * s;
        o.us[i] = f32_to_bf16_rne(q);
    }
    uint4* dst = (uint4*)(qw + (size_t)row * K_TOT + col);
    dst[0] = o.q[0];
    dst[1] = o.q[1];
}

// ---------------------------------------------------------------------------
// 256x256 bf16 GEMM — flattened-read pipeline with cross-tile bg prefetch.
// Per phase issue: {af4 (+af4 @p0), bg(t+1) 2} -> CU LDS issue 80/48/48/16
// reads across p0..p3 (vs 128/32/32/0 before).  bg(t+1) read from LDS during
// tile t (register double-buffer bgA/bgB); requires B staged 3 tiles ahead
// (B(t+3) at p2/p3) into the 3-slot rotation -- B(t)'s slot is free because
// bg(t) lives in registers.
// lgkm waits (6,6,6,2): p0 drains bg(t)[6:8]+afX(own,4); p1 drains afY+bg[0:2];
// p2 drains afX+bg[2:4]; p3 drains afY+bg[4:6], leaves bg[6:8] for next p0.
// vmcnt(4)@p3 drains B(t+2)+A(t+1), keeps B(t+3) (12 in flight).
// Barriers: end-p1 (bg-read vs B-stage WAR on recycled slot), end-p3 (RAW).
// ---------------------------------------------------------------------------
#define LDSA(tb, row, colus) \
    (*(const bf16x8*)&As[tb][row][(colus) ^ (((row) & 7) << 3)])
#define LDSB(slot, row, colus) \
    (*(const bf16x8*)&Bs[slot][row][(colus) ^ (((row) & 7) << 3)])

#define STAGE_A(tb, hh, li, tt)                                                          \
    async_copy16(Agbase + (size_t)((hh) * 128 + (li) * 64) * K_TOT + (size_t)(tt) * 64,  \
                 (char*)&As[0][0][0] + (tb) * 32768 + (hh) * 16384 + (li) * 8192 + (wv << 10));
#define STAGE_B(slot, hh, li, tt)                                                        \
    async_copy16(Bgbase + (size_t)((hh) * 128 + (li) * 64) * K_TOT + (size_t)(tt) * 64,  \
                 (char*)&Bs[0][0][0] + (size_t)(slot) * 32768 + (hh) * 16384 + (li) * 8192 + (wv << 10));
#define STAGE_A2(tb, hh, tt)    { STAGE_A(tb, hh, 0, tt) STAGE_A(tb, hh, 1, tt) }
#define STAGE_B2(slot, hh, tt)  { STAGE_B(slot, hh, 0, tt) STAGE_B(slot, hh, 1, tt) }

#define WAITLG(N) { asm volatile("s_waitcnt lgkmcnt(" #N ")" ::: "memory"); __builtin_amdgcn_sched_barrier(0); }

// read the 4 A-fragments of row-pair q (rows q*32, q*32+16; k lo/hi halves)
#define RD_AF(DST, tb, q) {                                   \
    DST[0] = LDSA(tb, ab + (q) * 32,      h8);                \
    DST[1] = LDSA(tb, ab + (q) * 32,      32 + h8);           \
    DST[2] = LDSA(tb, ab + (q) * 32 + 16, h8);                \
    DST[3] = LDSA(tb, ab + (q) * 32 + 16, 32 + h8); }

// read the 2 B-fragments of n-group j from slot
#define RD_BG2(DST, slot, j) {                                                \
    const int bb_ = wcn * 64 + (j) * 16 + r;                                  \
    DST[j][0] = LDSB(slot, bb_, h8);  DST[j][1] = LDSB(slot, bb_, 32 + h8); }

#define MFMA_PH(i0, AF, BGC)                                                              \
    __builtin_amdgcn_s_setprio(1);                                                        \
    _Pragma("unroll")                                                                     \
    for (int j = 0; j < 4; ++j) {                                                         \
        acc[i0][j]     = __builtin_amdgcn_mfma_f32_16x16x32_bf16(AF[0], BGC[j][0], acc[i0][j], 0, 0, 0);     \
        acc[i0][j]     = __builtin_amdgcn_mfma_f32_16x16x32_bf16(AF[1], BGC[j][1], acc[i0][j], 0, 0, 0);     \
        acc[(i0)+1][j] = __builtin_amdgcn_mfma_f32_16x16x32_bf16(AF[2], BGC[j][0], acc[(i0)+1][j], 0, 0, 0); \
        acc[(i0)+1][j] = __builtin_amdgcn_mfma_f32_16x16x32_bf16(AF[3], BGC[j][1], acc[(i0)+1][j], 0, 0, 0); \
    }                                                                                     \
    __builtin_amdgcn_s_setprio(0);

// One K-tile.  BGC: bg(t) regs (consumed); BGN: bg(t+1) regs (filled, 2/phase).
// STA: stage A(t+1); STB: stage B(t+3); RDBG: fill BGN; VMC: 4/0/-1.
// L0..L3: lgkm counts (steady 6,6,6,2; final tile 4,4,4,0).
#define TILE_BODY(tb, t, BGC, BGN, STA, STB, RDBG, VMC, L0, L1, L2, L3)                   \
  {                                                                                       \
    /* -- p0 -- */                                                                        \
    RD_AF(afX, tb, 0)                                                                     \
    __builtin_amdgcn_sched_barrier(0);   /* afX must be oldest (drain boundary) */        \
    RD_AF(afY, tb, 1)                                                                     \
    if (RDBG) RD_BG2(BGN, brd, 0)                                                         \
    if (STA) STAGE_A2(tb ^ 1, 0, (t) + 1)                                                 \
    WAITLG(L0)                                                                            \
    MFMA_PH(0, afX, BGC)                                                                  \
    /* -- p1 -- */                                                                        \
    RD_AF(afX, tb, 2)                                                                     \
    if (RDBG) RD_BG2(BGN, brd, 1)                                                         \
    if (STA) STAGE_A2(tb ^ 1, 1, (t) + 1)                                                 \
    WAITLG(L1)                                                                            \
    MFMA_PH(2, afY, BGC)                                                                  \
    __builtin_amdgcn_s_barrier();  /* all bg(t+1) reads served -> slot recycle safe */    \
    /* -- p2 -- */                                                                        \
    RD_AF(afY, tb, 3)                                                                     \
    if (RDBG) RD_BG2(BGN, brd, 2)                                                         \
    if (STB) STAGE_B2(bwr, 0, (t) + 3)                                                    \
    WAITLG(L2)                                                                            \
    MFMA_PH(4, afX, BGC)                                                                  \
    /* -- p3 -- */                                                                        \
    if (RDBG) RD_BG2(BGN, brd, 3)                                                         \
    if (STB) STAGE_B2(bwr, 1, (t) + 3)                                                    \
    WAITLG(L3)                                                                            \
    MFMA_PH(6, afY, BGC)                                                                  \
    if ((VMC) == 4)      { asm volatile("s_waitcnt vmcnt(4)" ::: "memory"); }             \
    else if ((VMC) == 0) { asm volatile("s_waitcnt vmcnt(0)" ::: "memory"); }             \
    __builtin_amdgcn_s_barrier();  /* staged tiles collectively visible */                \
  }

#define ROT { brd = (brd == 2) ? 0 : brd + 1;  bwr = (bwr == 2) ? 0 : bwr + 1; }

__global__ __launch_bounds__(512, 2) void gemm_pipe6_kernel(
    const ushort* __restrict__ A,    // [M][K] bf16 bits
    const ushort* __restrict__ Bt,   // [N][K] bf16 bits
    const float* __restrict__ bias,  // [N]
    float* __restrict__ C) {         // [M][N]

    __shared__ ushort As[2][256][64];   // 64 KB
    __shared__ ushort Bs[3][256][64];   // 96 KB (3-slot B rotation)

    const int tid  = threadIdx.x;
    const int lane = tid & 63;
    const int wv   = tid >> 6;          // wave 0..7
    const int wmr  = wv >> 2;           // 0..1  (M)
    const int wcn  = wv & 3;            // 0..3  (N)
    const int r    = lane & 15;
    const int h8   = (lane >> 4) << 3;  // 0,8,16,24 (ushort col of k-frag)

    // bijective XCD swizzle (nwg = 512)
    const int nbn  = N_TOT / 256;                 // 8
    const int nwg  = (M_TOT / 256) * nbn;         // 512
    const int cpx  = nwg >> 3;
    const int swz  = (blockIdx.x & 7) * cpx + (blockIdx.x >> 3);
    const int brow = (swz / nbn) * 256;
    const int bcol = (swz % nbn) * 256;

    // staging: thread -> row tid>>3 of each 64-row group, 16B at pre-swizzled col
    const int srow = tid >> 3;
    const int scol = (((tid & 7) ^ (srow & 7)) << 3);
    const ushort* Agbase = A  + (size_t)(brow + srow) * K_TOT + scol;
    const ushort* Bgbase = Bt + (size_t)(bcol + srow) * K_TOT + scol;

    const int ab = wmr * 128 + r;       // wave's A row base

    f32x4 acc[8][4];
    const f32x4 zero = {0.f, 0.f, 0.f, 0.f};
    #pragma unroll
    for (int i = 0; i < 8; ++i)
        #pragma unroll
        for (int j = 0; j < 4; ++j) acc[i][j] = zero;

    // ---- prologue: A(0)->As0, B(0)/B(1)/B(2)->slots 0/1/2; vmcnt(4) keeps
    //      B(2) in flight; barrier; preload bg(0)->bgA (drained at tile0 p0) --
    STAGE_A2(0, 0, 0) STAGE_A2(0, 1, 0)
    STAGE_B2(0, 0, 0) STAGE_B2(0, 1, 0)
    STAGE_B2(1, 0, 1) STAGE_B2(1, 1, 1)
    STAGE_B2(2, 0, 2) STAGE_B2(2, 1, 2)
    asm volatile("s_waitcnt vmcnt(4)" ::: "memory");
    __builtin_amdgcn_s_barrier();

    bf16x8 afX[4], afY[4];
    bf16x8 bgA[4][2], bgB[4][2];
    RD_BG2(bgA, 0, 0) RD_BG2(bgA, 0, 1) RD_BG2(bgA, 0, 2) RD_BG2(bgA, 0, 3)
    __builtin_amdgcn_sched_barrier(0);

    int brd = 1;   // bg(t+1) read slot = (t+1)%3
    int bwr = 0;   // B(t+3) stage slot = (t+3)%3

    for (int t = 0; t < 28; t += 2) {
        TILE_BODY(0, t,     bgA, bgB, 1, 1, 1, 4, 6, 6, 6, 2)
        ROT
        TILE_BODY(1, t + 1, bgB, bgA, 1, 1, 1, 4, 6, 6, 6, 2)
        ROT
    }
    TILE_BODY(0, 28, bgA, bgB, 1, 1, 1, 4, 6, 6, 6, 2)   // stages B(31); leaves it in flight
    ROT
    TILE_BODY(1, 29, bgB, bgA, 1, 0, 1, 0, 6, 6, 6, 2)   // stage A(30); drain B(31)+A(30)
    ROT
    TILE_BODY(0, 30, bgA, bgB, 1, 0, 1, 0, 6, 6, 6, 2)   // stage A(31); read bg(31); drain
    ROT
    TILE_BODY(1, 31, bgB, bgA, 0, 0, 0, -1, 4, 4, 4, 0)  // pure compute

    // ---- epilogue: bias + store (C/D layout: col=lane&15, row=(lane>>4)*4+reg)
    const int hq = (lane >> 4) * 4;
    float bv[4];
    #pragma unroll
    for (int j = 0; j < 4; ++j) bv[j] = bias[bcol + wcn * 64 + j * 16 + r];
    #pragma unroll
    for (int i = 0; i < 8; ++i) {
        const int row0 = brow + wmr * 128 + i * 16 + hq;
        #pragma unroll
        for (int j = 0; j < 4; ++j) {
            const int col = bcol + wcn * 64 + j * 16 + r;
            #pragma unroll
            for (int jj = 0; jj < 4; ++jj)
                C[(size_t)(row0 + jj) * N_TOT + col] = acc[i][j][jj] + bv[j];
        }
    }
}

extern "C" void kernel_launch(void* const* d_in, const int* in_sizes, int n_in,
                              void* d_out, int out_size, void* d_ws, size_t ws_size,
                              hipStream_t stream) {
    const float* x    = (const float*)d_in[0];   // [4,4096,2048]
    const float* wgt  = (const float*)d_in[1];   // [2048,2048]
    const float* bias = (const float*)d_in[2];   // [2048]
    float* out = (float*)d_out;                  // [4,4096,2048]

    ushort* qx = (ushort*)d_ws;                          // 64 MB
    ushort* qw = qx + (size_t)M_TOT * K_TOT;             // 8 MB

    quant_x_kernel<<<(M_TOT * K_TOT / 4) / 256, 256, 0, stream>>>(x, qx);
    quant_w_kernel<<<(64 * 64 * 64) / 256, 256, 0, stream>>>(wgt, qw);
    gemm_pipe6_kernel<<<(M_TOT / 256) * (N_TOT / 256), 512, 0, stream>>>(qx, qw, bias, out);
}